// Round 10
// baseline (256.295 us; speedup 1.0000x reference)
//
#include <hip/hip_runtime.h>
#include <math.h>

#define BATCH 4
#define SEQ   2048
#define DMODEL 1024
#define HEADS 16
#define DHEAD 64
#define SCALE 0.03125f                 // DIM^-0.5 = 1/32
#define KEXP  0.045084220027780106f    // SCALE * log2(e)
#define QKV_ELEMS (BATCH * HEADS * SEQ * DHEAD)  // 8388608 per tensor

typedef __attribute__((ext_vector_type(8))) short short8;
typedef __attribute__((ext_vector_type(4))) float floatx4;
typedef unsigned int u32;

__device__ __forceinline__ unsigned short f2bf(float f) {
  union { float f; unsigned u; } v;
  v.f = f;
  return (unsigned short)((v.u + 0x7FFFu + ((v.u >> 16) & 1u)) >> 16);
}

__device__ __forceinline__ float fast_exp2(float x) {
#if __has_builtin(__builtin_amdgcn_exp2f)
  return __builtin_amdgcn_exp2f(x);
#else
  return __expf(x * 0.6931471805599453f);
#endif
}

// pack two fp32 -> bf16x2 in one u32 (low = p0, high = p1)
__device__ __forceinline__ u32 pack_bf16(float p0, float p1) {
#if __has_builtin(__builtin_amdgcn_cvt_pk_bf16_f32)
  typedef __bf16 bf16x2 __attribute__((ext_vector_type(2)));
  bf16x2 t = __builtin_amdgcn_cvt_pk_bf16_f32(p0, p1);
  u32 r;
  __builtin_memcpy(&r, &t, 4);
  return r;
#else
  u32 a0 = __float_as_uint(p0) + 0x8000u;
  u32 a1 = __float_as_uint(p1) + 0x8000u;
  return __builtin_amdgcn_perm(a1, a0, 0x07060302);
#endif
}

// async global->LDS, 16B per lane; lds dest is wave-uniform base + lane*16.
__device__ __forceinline__ void async_ld16(const void* g, void* l) {
  __builtin_amdgcn_global_load_lds(
      (const __attribute__((address_space(1))) u32*)g,
      (__attribute__((address_space(3))) u32*)l, 16, 0, 0);
}

// ---------------------------------------------------------------------------
// Merged prep: x->bf16 (blocks 0..8191), wqkv transpose (8192..11263),
// wout transpose (11264..12287).
// ---------------------------------------------------------------------------
__device__ __forceinline__ void trans_tile(const float* __restrict__ W,
                                           unsigned short* __restrict__ WT,
                                           int K, int N, int n0, int k0,
                                           float (*tile)[33]) {
  const int tx = threadIdx.x & 31, ty = threadIdx.x >> 5;  // ty 0..7
#pragma unroll
  for (int i = 0; i < 4; ++i)
    tile[ty + i * 8][tx] = W[(size_t)(k0 + ty + i * 8) * N + n0 + tx];
  __syncthreads();
#pragma unroll
  for (int i = 0; i < 4; ++i)
    WT[(size_t)(n0 + ty + i * 8) * K + k0 + tx] = f2bf(tile[tx][ty + i * 8]);
}

__global__ __launch_bounds__(256) void prep_kernel(
    const float* __restrict__ x, const float* __restrict__ wqkv,
    const float* __restrict__ wout, unsigned short* __restrict__ xb,
    unsigned short* __restrict__ wqkvT, unsigned short* __restrict__ woutT) {
  __shared__ float tile[32][33];
  const int bx = blockIdx.x;
  if (bx < 8192) {
    size_t i = ((size_t)bx * 256 + threadIdx.x) * 4;
    float4 v = *(const float4*)(x + i);
    ushort4 o;
    o.x = f2bf(v.x); o.y = f2bf(v.y); o.z = f2bf(v.z); o.w = f2bf(v.w);
    *(ushort4*)(xb + i) = o;
  } else if (bx < 11264) {
    int t = bx - 8192;
    trans_tile(wqkv, wqkvT, 1024, 3072, (t % 96) * 32, (t / 96) * 32, tile);
  } else {
    int t = bx - 11264;
    trans_tile(wout, woutT, 1024, 1024, (t % 32) * 32, (t / 32) * 32, tile);
  }
}

// ---------------------------------------------------------------------------
// Shared GEMM core: 256x128 tile, BK=64, 512 threads (8 waves, 2M x 4N),
// TRIPLE-buffered LDS (3 x 48KB = 144KB), 2 phases per K-tile, counted
// vmcnt(6) (stage tile u+2 at Ph1 of iter u; oldest 6 loads = tile u+1
// guaranteed at Ph2-end vmcnt), setprio around 16-MFMA clusters, XOR k-chunk
// swizzle on staging source + fragment reads.
// ---------------------------------------------------------------------------
#define G_BAR() __builtin_amdgcn_s_barrier()
#define G_LGKM0() asm volatile("s_waitcnt lgkmcnt(0)" ::: "memory")

#define STAGE_TILE(t)                                                          \
  do {                                                                         \
    const unsigned short* Ab =                                                 \
        A + (size_t)(m0 + srow) * 1024 + (t) * 64 + schunk * 8;                \
    const unsigned short* Bb =                                                 \
        BT + (size_t)(n0 + srow) * 1024 + (t) * 64 + schunk * 8;               \
    unsigned short* sa = smemS + ((t) % 3) * 24576;                            \
    unsigned short* sb = sa + 16384;                                           \
    async_ld16(Ab, sa + tid * 8);                                              \
    async_ld16(Ab + 64 * 1024, sa + 4096 + tid * 8);                           \
    async_ld16(Ab + 128 * 1024, sa + 8192 + tid * 8);                          \
    async_ld16(Ab + 192 * 1024, sa + 12288 + tid * 8);                         \
    async_ld16(Bb, sb + tid * 8);                                              \
    async_ld16(Bb + 64 * 1024, sb + 4096 + tid * 8);                           \
  } while (0)

#define RD_A(SAp, mh)                                                          \
  do {                                                                         \
    _Pragma("unroll") for (int mi = 0; mi < 4; ++mi) {                         \
      a[mi][0] = *(const short8*)((SAp) + rowA + (mh)*4096 + mi * 1024 + cof0);\
      a[mi][1] = *(const short8*)((SAp) + rowA + (mh)*4096 + mi * 1024 + cof1);\
    }                                                                          \
  } while (0)

#define RD_B(SBp)                                                              \
  do {                                                                         \
    _Pragma("unroll") for (int ni = 0; ni < 2; ++ni) {                         \
      b[ni][0] = *(const short8*)((SBp) + rowB + ni * 1024 + cof0);            \
      b[ni][1] = *(const short8*)((SBp) + rowB + ni * 1024 + cof1);            \
    }                                                                          \
  } while (0)

#define CLUSTER(mh)                                                            \
  do {                                                                         \
    __builtin_amdgcn_s_setprio(1);                                             \
    _Pragma("unroll") for (int mi = 0; mi < 4; ++mi) {                         \
      _Pragma("unroll") for (int ni = 0; ni < 2; ++ni) {                       \
        acc[(mh)*4 + mi][ni] = __builtin_amdgcn_mfma_f32_16x16x32_bf16(        \
            a[mi][0], b[ni][0], acc[(mh)*4 + mi][ni], 0, 0, 0);                \
        acc[(mh)*4 + mi][ni] = __builtin_amdgcn_mfma_f32_16x16x32_bf16(        \
            a[mi][1], b[ni][1], acc[(mh)*4 + mi][ni], 0, 0, 0);                \
      }                                                                        \
    }                                                                          \
    __builtin_amdgcn_s_setprio(0);                                             \
  } while (0)

__device__ __forceinline__ void core256x128(
    const unsigned short* __restrict__ A, const unsigned short* __restrict__ BT,
    unsigned short* smemS, int m0, int n0, floatx4 (&acc)[8][2]) {
  const int tid = threadIdx.x;            // 0..511
  const int wave = tid >> 6, lane = tid & 63;
  const int Q4 = lane >> 4, L = lane & 15;
  const int wr = wave >> 2, wc = wave & 3;
  const int srow = tid >> 3;                   // 0..63
  const int schunk = (tid & 7) ^ (srow & 7);   // swizzled k-chunk
  const int xorL = L & 7;
  const int cof0 = (Q4 ^ xorL) * 8;
  const int cof1 = ((4 + Q4) ^ xorL) * 8;
  const int rowA = wr * 8192 + L * 64;         // wave M-half base (rows*64)
  const int rowB = wc * 2048 + L * 64;         // wave N-slab base

  short8 a[4][2], b[2][2];
#pragma unroll
  for (int mt = 0; mt < 8; ++mt)
#pragma unroll
    for (int nt = 0; nt < 2; ++nt) acc[mt][nt] = (floatx4){0.f, 0.f, 0.f, 0.f};

  STAGE_TILE(0);
  STAGE_TILE(1);
  asm volatile("s_waitcnt vmcnt(6)" ::: "memory");
  G_BAR();

#pragma unroll
  for (int u = 0; u < 16; ++u) {
    unsigned short* SA = smemS + (u % 3) * 24576;
    unsigned short* SB = SA + 16384;
    // ---- Ph1: read A(mh0)+B of tile u; stage tile u+2
    RD_A(SA, 0);
    RD_B(SB);
    if (u + 2 < 16) STAGE_TILE(u + 2);
    G_BAR(); G_LGKM0();
    CLUSTER(0);
    G_BAR();
    // ---- Ph2: read A(mh1); counted vmcnt before closing barrier
    RD_A(SA, 1);
    G_BAR(); G_LGKM0();
    CLUSTER(1);
    if (u + 2 < 16) asm volatile("s_waitcnt vmcnt(6)" ::: "memory");
    else            asm volatile("s_waitcnt vmcnt(0)" ::: "memory");
    G_BAR();
  }
}

// ---------------------------------------------------------------------------
// QKV GEMM: grid 32x24 = 768 blocks (exactly 3 full rounds of 256 CUs).
// nblk 0..7 -> Q (scaled by KEXP), 8..15 -> K (repacked to [B,H,N,64] rows),
// 16..23 -> V transposed into vtg [B,H,64,N] (pc-permuted tokens).
// ---------------------------------------------------------------------------
__global__ __launch_bounds__(512, 2) void gemm_qkv_kernel(
    const unsigned short* __restrict__ A, const unsigned short* __restrict__ BT,
    unsigned short* __restrict__ qk, unsigned short* __restrict__ vtg) {
  __shared__ __align__(16) unsigned char smem[147456];  // 3 x 48KB
  unsigned short* smemS = (unsigned short*)smem;

  const int tid = threadIdx.x;
  const int wave = tid >> 6, lane = tid & 63;
  const int Q4 = lane >> 4, L = lane & 15;
  const int wr = wave >> 2, wc = wave & 3;

  // bijective XCD swizzle over 768 blocks (768 % 8 == 0)
  const int flat = blockIdx.y * 24 + blockIdx.x;
  const int swz = (flat & 7) * 96 + (flat >> 3);
  const int mblk = swz / 24, nblk = swz % 24;
  const int m0 = mblk * 256, n0 = nblk * 128;

  floatx4 acc[8][2];
  core256x128(A, BT, smemS, m0, n0, acc);

  // ------------------------------- epilogue -------------------------------
  const int bb = m0 >> 11;
  const int ntok0 = m0 & 2047;
  unsigned short* T = smemS;

  if (nblk < 16) {
    // Q/K: repack to [B,H,N,64] rows via T[256][136] (single pass)
    const float qsc = (nblk < 8) ? KEXP : 1.0f;
    unsigned short* dst = qk + (size_t)(nblk >> 3) * QKV_ELEMS;
    const int h0 = (nblk & 7) * 2;
#pragma unroll
    for (int mt = 0; mt < 8; ++mt)
#pragma unroll
      for (int nt = 0; nt < 2; ++nt) {
        const int col = wc * 32 + nt * 16 + L;
        const int tokl = wr * 128 + mt * 16 + Q4 * 4;
#pragma unroll
        for (int r = 0; r < 4; ++r)
          T[(tokl + r) * 136 + col] = f2bf(acc[mt][nt][r] * qsc);
      }
    __syncthreads();
#pragma unroll
    for (int it2 = 0; it2 < 8; ++it2) {
      int slot = it2 * 512 + tid;
      int tok = slot >> 4, ch = slot & 15;
      int hh = ch >> 3, inner = ch & 7;
      *(short8*)(dst +
                 (((size_t)((bb * 16 + h0 + hh) * 2048 + ntok0 + tok)) << 6) +
                 inner * 8) = *(const short8*)&T[tok * 136 + hh * 64 + inner * 8];
    }
  } else {
    // V: transpose to vtg [B,H,64,N] with pc-permuted tokens via T[128][264]
    const int nv0 = (nblk - 16) * 128;
#pragma unroll
    for (int mt = 0; mt < 8; ++mt)
#pragma unroll
      for (int nt = 0; nt < 2; ++nt) {
        const int col = wc * 32 + nt * 16 + L;
#pragma unroll
        for (int r = 0; r < 4; ++r) {
          int tok = wr * 128 + mt * 16 + Q4 * 4 + r;
          int pcm = (tok & ~31) | ((tok & 15) << 1) | ((tok >> 4) & 1);
          T[col * 264 + pcm] = f2bf(acc[mt][nt][r]);
        }
      }
    __syncthreads();
#pragma unroll
    for (int it2 = 0; it2 < 8; ++it2) {
      int slot = it2 * 512 + tid;
      int col = slot >> 5, ch = slot & 31;
      int nc = nv0 + col;
      *(short8*)(vtg +
                 (((size_t)((bb * 16 + (nc >> 6)) * 64 + (nc & 63))) << 11) +
                 ntok0 + ch * 8) = *(const short8*)&T[col * 264 + ch * 8];
    }
  }
}

// ---------------------------------------------------------------------------
// Output GEMM: grid 32x8 = 256 blocks (exactly 1 full round of 256 CUs).
// ---------------------------------------------------------------------------
__global__ __launch_bounds__(512, 2) void gemm_out_kernel(
    const unsigned short* __restrict__ A, const unsigned short* __restrict__ BT,
    const float* __restrict__ bias, float* __restrict__ C) {
  __shared__ __align__(16) unsigned char smem[147456];
  unsigned short* smemS = (unsigned short*)smem;

  const int tid = threadIdx.x;
  const int wave = tid >> 6, lane = tid & 63;
  const int Q4 = lane >> 4, L = lane & 15;
  const int wr = wave >> 2, wc = wave & 3;

  const int flat = blockIdx.y * 8 + blockIdx.x;
  const int swz = (flat & 7) * 32 + (flat >> 3);
  const int m0 = (swz >> 3) * 256, n0 = (swz & 7) * 128;

  floatx4 acc[8][2];
  core256x128(A, BT, smemS, m0, n0, acc);

#pragma unroll
  for (int mt = 0; mt < 8; ++mt) {
#pragma unroll
    for (int nt = 0; nt < 2; ++nt) {
      int nc = n0 + wc * 32 + nt * 16 + L;
      float bv = bias[nc];
#pragma unroll
      for (int r = 0; r < 4; ++r) {
        int m = m0 + wr * 128 + mt * 16 + Q4 * 4 + r;
        C[(size_t)m * DMODEL + nc] = acc[mt][nt][r] + bv;
      }
    }
  }
}

#undef STAGE_TILE
#undef RD_A
#undef RD_B
#undef CLUSTER
#undef G_BAR
#undef G_LGKM0

// ---------------------------------------------------------------------------
// Flash attention, SWAPPED-QK^T (T12) + ILP-INTERLEAVED COMPUTE.
// R9 counters: MfmaUtil 40 + VALUBusy 46, dur ~= sum not max -> the MFMA and
// VALU pipes SERIALIZE. Cross-wave overlap is absent (R3/R6/R8 all refuted
// TLP), so overlap must come from intra-wave ILP. The old COMPUTE forced
// per-qs {QK -> exp -> PV} order with 24 setprio fences/tile. New COMPUTE:
// both qs's QK MFMAs first (8 independent), then both exp/pack blocks, then
// both PV clusters -- no setprio -- letting the scheduler hoist exp(qs0)
// under QK(qs1) and PV(qs0) under exp(qs1). Per-value math and each
// accumulator's MFMA order unchanged -> bitwise-identical output.
// LDS 32KB, grid 512, 8 waves. [Best prior: 80.2us @ R9.]
// ---------------------------------------------------------------------------
__global__ __launch_bounds__(512, 4) void attn_kernel(
    const unsigned short* __restrict__ Qb, const unsigned short* __restrict__ Kb,
    const unsigned short* __restrict__ Vtg, unsigned short* __restrict__ Op) {
  __shared__ __align__(16) unsigned short Ks[2][64 * 64];
  __shared__ __align__(16) unsigned short Vs[2][64 * 64];
  const int tid = threadIdx.x;
  const int wave = tid >> 6, lane = tid & 63;   // wave 0..7
  const int quad = lane >> 4, l16 = lane & 15;
  const int bh = blockIdx.x & 63, qt = blockIdx.x >> 6;  // qt 0..7
  const size_t base = (size_t)bh * SEQ * DHEAD;
  const int lrow = lane >> 3, ls = lane & 7;
  const int dblk = ls ^ (lrow & 7);
  const int sw = l16 & 7;

  const unsigned short* kbase = Kb + base;
  const unsigned short* vbase = Vtg + base;
  const int rowS = wave * 8 + lrow;  // staging row (chunk = wave)

  short8 onesf;
#pragma unroll
  for (int i = 0; i < 8; ++i) onesf[i] = (short)0x3F80;  // bf16 1.0

  short8 qf[2][2];
#pragma unroll
  for (int qs = 0; qs < 2; ++qs) {
    int qrow = qt * 256 + wave * 32 + qs * 16 + l16;
    qf[qs][0] = *(const short8*)(Qb + base + (size_t)qrow * DHEAD + quad * 8);
    qf[qs][1] =
        *(const short8*)(Qb + base + (size_t)qrow * DHEAD + 32 + quad * 8);
  }

  floatx4 o[2][4], lacc[2];
#pragma unroll
  for (int qs = 0; qs < 2; ++qs) {
    lacc[qs] = (floatx4){0.f, 0.f, 0.f, 0.f};
#pragma unroll
    for (int dt = 0; dt < 4; ++dt) o[qs][dt] = (floatx4){0.f, 0.f, 0.f, 0.f};
  }

#define STAGE(buf, kc)                                                         \
  do {                                                                         \
    async_ld16(kbase + (size_t)((kc)*64 + rowS) * DHEAD + dblk * 8,            \
               &Ks[buf][wave * 512]);                                          \
    async_ld16(vbase + (size_t)rowS * SEQ + (kc)*64 + dblk * 8,                \
               &Vs[buf][wave * 512]);                                          \
  } while (0)

#define COMPUTE(buf)                                                           \
  do {                                                                         \
    _Pragma("unroll") for (int kc2 = 0; kc2 < 2; ++kc2) {                      \
      const int krow = kc2 * 32;                                               \
      short8 kf00 =                                                            \
          *(short8*)(&Ks[buf][0] + (krow + l16) * 64 + ((quad ^ sw) * 8));     \
      short8 kf01 = *(short8*)(&Ks[buf][0] + (krow + l16) * 64 +               \
                               (((4 + quad) ^ sw) * 8));                       \
      short8 kf10 = *(short8*)(&Ks[buf][0] + (krow + 16 + l16) * 64 +          \
                               ((quad ^ sw) * 8));                             \
      short8 kf11 = *(short8*)(&Ks[buf][0] + (krow + 16 + l16) * 64 +          \
                               (((4 + quad) ^ sw) * 8));                       \
      short8 vf[4];                                                            \
      _Pragma("unroll") for (int dt = 0; dt < 4; ++dt) vf[dt] =                \
          *(short8*)(&Vs[buf][0] + (dt * 16 + l16) * 64 +                      \
                     (((kc2 * 4 + quad) ^ sw) * 8));                           \
      floatx4 s0[2], s1[2];                                                    \
      _Pragma("unroll") for (int qs = 0; qs < 2; ++qs) {                       \
        s0[qs] = (floatx4){0.f, 0.f, 0.f, 0.f};                                \
        s1[qs] = (floatx4){0.f, 0.f, 0.f, 0.f};                                \
        s0[qs] = __builtin_amdgcn_mfma_f32_16x16x32_bf16(kf00, qf[qs][0],      \
                                                         s0[qs], 0, 0, 0);     \
        s0[qs] = __builtin_amdgcn_mfma_f32_16x16x32_bf16(kf01, qf[qs][1],      \
                                                         s0[qs], 0, 0, 0);     \
        s1[qs] = __builtin_amdgcn_mfma_f32_16x16x32_bf16(kf10, qf[qs][0],      \
                                                         s1[qs], 0, 0, 0);     \
        s1[qs] = __builtin_amdgcn_mfma_f32_16x16x32_bf16(kf11, qf[qs][1],      \
                                                         s1[qs], 0, 0, 0);     \
      }                                                                        \
      short8 pf[2];                                                            \
      _Pragma("unroll") for (int qs = 0; qs < 2; ++qs) {                       \
        union { short8 s8; u32 u[4]; } pu;                                     \
        _Pragma("unroll") for (int r = 0; r < 4; ++r) {                        \
          pu.u[r] = pack_bf16(fast_exp2(s0[qs][r]), fast_exp2(s1[qs][r]));     \
        }                                                                      \
        pf[qs] = pu.s8;                                                        \
      }                                                                        \
      _Pragma("unroll") for (int qs = 0; qs < 2; ++qs) {                       \
        lacc[qs] = __builtin_amdgcn_mfma_f32_16x16x32_bf16(pf[qs], onesf,      \
                                                           lacc[qs], 0, 0, 0); \
        _Pragma("unroll") for (int dt = 0; dt < 4; ++dt) o[qs][dt] =           \
            __builtin_amdgcn_mfma_f32_16x16x32_bf16(pf[qs], vf[dt],            \
                                                    o[qs][dt], 0, 0, 0);       \
      }                                                                        \
    }                                                                          \
  } while (0)

  STAGE(0, 0);
  for (int kc = 0; kc < SEQ / 64; kc += 2) {
    __syncthreads();  // buf0 loads complete; all waves done reading buf1
    if (kc + 1 < SEQ / 64) STAGE(1, kc + 1);
    COMPUTE(0);
    __syncthreads();  // buf1 loads complete; all waves done reading buf0
    if (kc + 2 < SEQ / 64) STAGE(0, kc + 2);
    COMPUTE(1);
  }
#undef STAGE
#undef COMPUTE

  const int b = bh >> 4, h = bh & 15;
#pragma unroll
  for (int qs = 0; qs < 2; ++qs) {
#pragma unroll
    for (int r = 0; r < 4; ++r) {
      float inv = 1.f / lacc[qs][r];
      int n = qt * 256 + wave * 32 + qs * 16 + quad * 4 + r;
      size_t rowbase = ((size_t)(b * SEQ + n)) * DMODEL + h * DHEAD;
#pragma unroll
      for (int dt = 0; dt < 4; ++dt)
        Op[rowbase + dt * 16 + l16] = f2bf(o[qs][dt][r] * inv);
    }
  }
}

extern "C" void kernel_launch(void* const* d_in, const int* in_sizes, int n_in,
                              void* d_out, int out_size, void* d_ws,
                              size_t ws_size, hipStream_t stream) {
  const float* x = (const float*)d_in[0];
  const float* w_qkv = (const float*)d_in[1];
  const float* w_out = (const float*)d_in[2];
  const float* b_out = (const float*)d_in[3];
  float* out = (float*)d_out;

  unsigned short* ws = (unsigned short*)d_ws;
  unsigned short* xb = ws;                         // 8388608
  unsigned short* wqkvT = xb + 8388608;            // 3145728  [3072][1024]
  unsigned short* woutT = wqkvT + 3145728;         // 1048576  [1024][1024]
  unsigned short* qb = woutT + 1048576;            // [B,H,N,64] (pre-scaled)
  unsigned short* kb = qb + QKV_ELEMS;             // [B,H,N,64]
  unsigned short* vtg = kb + QKV_ELEMS;            // [B,H,64,N] permuted cols
  unsigned short* op = vtg + QKV_ELEMS;            // [B,N,1024]

  prep_kernel<<<dim3(12288), dim3(256), 0, stream>>>(x, w_qkv, w_out, xb,
                                                     wqkvT, woutT);
  gemm_qkv_kernel<<<dim3(24, 32), dim3(512), 0, stream>>>(xb, wqkvT, qb, vtg);
  attn_kernel<<<dim3(512), dim3(512), 0, stream>>>(qb, kb, vtg, op);
  gemm_out_kernel<<<dim3(8, 32), dim3(512), 0, stream>>>(op, woutT, b_out, out);
}

// Round 11
// 249.268 us; speedup vs baseline: 1.0282x; 1.0282x over previous
//
#include <hip/hip_runtime.h>
#include <math.h>

#define BATCH 4
#define SEQ   2048
#define DMODEL 1024
#define HEADS 16
#define DHEAD 64
#define SCALE 0.03125f                 // DIM^-0.5 = 1/32
#define KEXP  0.045084220027780106f    // SCALE * log2(e)
#define QKV_ELEMS (BATCH * HEADS * SEQ * DHEAD)  // 8388608 per tensor

typedef __attribute__((ext_vector_type(8))) short short8;
typedef __attribute__((ext_vector_type(4))) float floatx4;
typedef unsigned int u32;

__device__ __forceinline__ unsigned short f2bf(float f) {
  union { float f; unsigned u; } v;
  v.f = f;
  return (unsigned short)((v.u + 0x7FFFu + ((v.u >> 16) & 1u)) >> 16);
}

__device__ __forceinline__ float fast_exp2(float x) {
#if __has_builtin(__builtin_amdgcn_exp2f)
  return __builtin_amdgcn_exp2f(x);
#else
  return __expf(x * 0.6931471805599453f);
#endif
}

// pack two fp32 -> bf16x2 in one u32 (low = p0, high = p1)
__device__ __forceinline__ u32 pack_bf16(float p0, float p1) {
#if __has_builtin(__builtin_amdgcn_cvt_pk_bf16_f32)
  typedef __bf16 bf16x2 __attribute__((ext_vector_type(2)));
  bf16x2 t = __builtin_amdgcn_cvt_pk_bf16_f32(p0, p1);
  u32 r;
  __builtin_memcpy(&r, &t, 4);
  return r;
#else
  u32 a0 = __float_as_uint(p0) + 0x8000u;
  u32 a1 = __float_as_uint(p1) + 0x8000u;
  return __builtin_amdgcn_perm(a1, a0, 0x07060302);
#endif
}

// async global->LDS, 16B per lane; lds dest is wave-uniform base + lane*16.
__device__ __forceinline__ void async_ld16(const void* g, void* l) {
  __builtin_amdgcn_global_load_lds(
      (const __attribute__((address_space(1))) u32*)g,
      (__attribute__((address_space(3))) u32*)l, 16, 0, 0);
}

// ---------------------------------------------------------------------------
// Merged prep: x->bf16 (blocks 0..8191), wqkv transpose (8192..11263),
// wout transpose (11264..12287).
// ---------------------------------------------------------------------------
__device__ __forceinline__ void trans_tile(const float* __restrict__ W,
                                           unsigned short* __restrict__ WT,
                                           int K, int N, int n0, int k0,
                                           float (*tile)[33]) {
  const int tx = threadIdx.x & 31, ty = threadIdx.x >> 5;  // ty 0..7
#pragma unroll
  for (int i = 0; i < 4; ++i)
    tile[ty + i * 8][tx] = W[(size_t)(k0 + ty + i * 8) * N + n0 + tx];
  __syncthreads();
#pragma unroll
  for (int i = 0; i < 4; ++i)
    WT[(size_t)(n0 + ty + i * 8) * K + k0 + tx] = f2bf(tile[tx][ty + i * 8]);
}

__global__ __launch_bounds__(256) void prep_kernel(
    const float* __restrict__ x, const float* __restrict__ wqkv,
    const float* __restrict__ wout, unsigned short* __restrict__ xb,
    unsigned short* __restrict__ wqkvT, unsigned short* __restrict__ woutT) {
  __shared__ float tile[32][33];
  const int bx = blockIdx.x;
  if (bx < 8192) {
    size_t i = ((size_t)bx * 256 + threadIdx.x) * 4;
    float4 v = *(const float4*)(x + i);
    ushort4 o;
    o.x = f2bf(v.x); o.y = f2bf(v.y); o.z = f2bf(v.z); o.w = f2bf(v.w);
    *(ushort4*)(xb + i) = o;
  } else if (bx < 11264) {
    int t = bx - 8192;
    trans_tile(wqkv, wqkvT, 1024, 3072, (t % 96) * 32, (t / 96) * 32, tile);
  } else {
    int t = bx - 11264;
    trans_tile(wout, woutT, 1024, 1024, (t % 32) * 32, (t / 32) * 32, tile);
  }
}

// ---------------------------------------------------------------------------
// Shared GEMM core: 256x128 tile, BK=64, 512 threads (8 waves, 2M x 4N),
// TRIPLE-buffered LDS (3 x 48KB = 144KB), 2 phases per K-tile, counted
// vmcnt(6) (stage tile u+2 at Ph1 of iter u; oldest 6 loads = tile u+1
// guaranteed at Ph2-end vmcnt), setprio around 16-MFMA clusters, XOR k-chunk
// swizzle on staging source + fragment reads.
// ---------------------------------------------------------------------------
#define G_BAR() __builtin_amdgcn_s_barrier()
#define G_LGKM0() asm volatile("s_waitcnt lgkmcnt(0)" ::: "memory")

#define STAGE_TILE(t)                                                          \
  do {                                                                         \
    const unsigned short* Ab =                                                 \
        A + (size_t)(m0 + srow) * 1024 + (t) * 64 + schunk * 8;                \
    const unsigned short* Bb =                                                 \
        BT + (size_t)(n0 + srow) * 1024 + (t) * 64 + schunk * 8;               \
    unsigned short* sa = smemS + ((t) % 3) * 24576;                            \
    unsigned short* sb = sa + 16384;                                           \
    async_ld16(Ab, sa + tid * 8);                                              \
    async_ld16(Ab + 64 * 1024, sa + 4096 + tid * 8);                           \
    async_ld16(Ab + 128 * 1024, sa + 8192 + tid * 8);                          \
    async_ld16(Ab + 192 * 1024, sa + 12288 + tid * 8);                         \
    async_ld16(Bb, sb + tid * 8);                                              \
    async_ld16(Bb + 64 * 1024, sb + 4096 + tid * 8);                           \
  } while (0)

#define RD_A(SAp, mh)                                                          \
  do {                                                                         \
    _Pragma("unroll") for (int mi = 0; mi < 4; ++mi) {                         \
      a[mi][0] = *(const short8*)((SAp) + rowA + (mh)*4096 + mi * 1024 + cof0);\
      a[mi][1] = *(const short8*)((SAp) + rowA + (mh)*4096 + mi * 1024 + cof1);\
    }                                                                          \
  } while (0)

#define RD_B(SBp)                                                              \
  do {                                                                         \
    _Pragma("unroll") for (int ni = 0; ni < 2; ++ni) {                         \
      b[ni][0] = *(const short8*)((SBp) + rowB + ni * 1024 + cof0);            \
      b[ni][1] = *(const short8*)((SBp) + rowB + ni * 1024 + cof1);            \
    }                                                                          \
  } while (0)

#define CLUSTER(mh)                                                            \
  do {                                                                         \
    __builtin_amdgcn_s_setprio(1);                                             \
    _Pragma("unroll") for (int mi = 0; mi < 4; ++mi) {                         \
      _Pragma("unroll") for (int ni = 0; ni < 2; ++ni) {                       \
        acc[(mh)*4 + mi][ni] = __builtin_amdgcn_mfma_f32_16x16x32_bf16(        \
            a[mi][0], b[ni][0], acc[(mh)*4 + mi][ni], 0, 0, 0);                \
        acc[(mh)*4 + mi][ni] = __builtin_amdgcn_mfma_f32_16x16x32_bf16(        \
            a[mi][1], b[ni][1], acc[(mh)*4 + mi][ni], 0, 0, 0);                \
      }                                                                        \
    }                                                                          \
    __builtin_amdgcn_s_setprio(0);                                             \
  } while (0)

__device__ __forceinline__ void core256x128(
    const unsigned short* __restrict__ A, const unsigned short* __restrict__ BT,
    unsigned short* smemS, int m0, int n0, floatx4 (&acc)[8][2]) {
  const int tid = threadIdx.x;            // 0..511
  const int wave = tid >> 6, lane = tid & 63;
  const int Q4 = lane >> 4, L = lane & 15;
  const int wr = wave >> 2, wc = wave & 3;
  const int srow = tid >> 3;                   // 0..63
  const int schunk = (tid & 7) ^ (srow & 7);   // swizzled k-chunk
  const int xorL = L & 7;
  const int cof0 = (Q4 ^ xorL) * 8;
  const int cof1 = ((4 + Q4) ^ xorL) * 8;
  const int rowA = wr * 8192 + L * 64;         // wave M-half base (rows*64)
  const int rowB = wc * 2048 + L * 64;         // wave N-slab base

  short8 a[4][2], b[2][2];
#pragma unroll
  for (int mt = 0; mt < 8; ++mt)
#pragma unroll
    for (int nt = 0; nt < 2; ++nt) acc[mt][nt] = (floatx4){0.f, 0.f, 0.f, 0.f};

  STAGE_TILE(0);
  STAGE_TILE(1);
  asm volatile("s_waitcnt vmcnt(6)" ::: "memory");
  G_BAR();

#pragma unroll
  for (int u = 0; u < 16; ++u) {
    unsigned short* SA = smemS + (u % 3) * 24576;
    unsigned short* SB = SA + 16384;
    // ---- Ph1: read A(mh0)+B of tile u; stage tile u+2
    RD_A(SA, 0);
    RD_B(SB);
    if (u + 2 < 16) STAGE_TILE(u + 2);
    G_BAR(); G_LGKM0();
    CLUSTER(0);
    G_BAR();
    // ---- Ph2: read A(mh1); counted vmcnt before closing barrier
    RD_A(SA, 1);
    G_BAR(); G_LGKM0();
    CLUSTER(1);
    if (u + 2 < 16) asm volatile("s_waitcnt vmcnt(6)" ::: "memory");
    else            asm volatile("s_waitcnt vmcnt(0)" ::: "memory");
    G_BAR();
  }
}

// ---------------------------------------------------------------------------
// QKV GEMM: grid 32x24 = 768 blocks (exactly 3 full rounds of 256 CUs).
// nblk 0..7 -> Q (scaled by KEXP), 8..15 -> K (repacked to [B,H,N,64] rows),
// 16..23 -> V transposed into vtg [B,H,64,N] (pc-permuted tokens).
// ---------------------------------------------------------------------------
__global__ __launch_bounds__(512, 2) void gemm_qkv_kernel(
    const unsigned short* __restrict__ A, const unsigned short* __restrict__ BT,
    unsigned short* __restrict__ qk, unsigned short* __restrict__ vtg) {
  __shared__ __align__(16) unsigned char smem[147456];  // 3 x 48KB
  unsigned short* smemS = (unsigned short*)smem;

  const int tid = threadIdx.x;
  const int wave = tid >> 6, lane = tid & 63;
  const int Q4 = lane >> 4, L = lane & 15;
  const int wr = wave >> 2, wc = wave & 3;

  // bijective XCD swizzle over 768 blocks (768 % 8 == 0)
  const int flat = blockIdx.y * 24 + blockIdx.x;
  const int swz = (flat & 7) * 96 + (flat >> 3);
  const int mblk = swz / 24, nblk = swz % 24;
  const int m0 = mblk * 256, n0 = nblk * 128;

  floatx4 acc[8][2];
  core256x128(A, BT, smemS, m0, n0, acc);

  // ------------------------------- epilogue -------------------------------
  const int bb = m0 >> 11;
  const int ntok0 = m0 & 2047;
  unsigned short* T = smemS;

  if (nblk < 16) {
    // Q/K: repack to [B,H,N,64] rows via T[256][136] (single pass)
    const float qsc = (nblk < 8) ? KEXP : 1.0f;
    unsigned short* dst = qk + (size_t)(nblk >> 3) * QKV_ELEMS;
    const int h0 = (nblk & 7) * 2;
#pragma unroll
    for (int mt = 0; mt < 8; ++mt)
#pragma unroll
      for (int nt = 0; nt < 2; ++nt) {
        const int col = wc * 32 + nt * 16 + L;
        const int tokl = wr * 128 + mt * 16 + Q4 * 4;
#pragma unroll
        for (int r = 0; r < 4; ++r)
          T[(tokl + r) * 136 + col] = f2bf(acc[mt][nt][r] * qsc);
      }
    __syncthreads();
#pragma unroll
    for (int it2 = 0; it2 < 8; ++it2) {
      int slot = it2 * 512 + tid;
      int tok = slot >> 4, ch = slot & 15;
      int hh = ch >> 3, inner = ch & 7;
      *(short8*)(dst +
                 (((size_t)((bb * 16 + h0 + hh) * 2048 + ntok0 + tok)) << 6) +
                 inner * 8) = *(const short8*)&T[tok * 136 + hh * 64 + inner * 8];
    }
  } else {
    // V: transpose to vtg [B,H,64,N] with pc-permuted tokens via T[128][264]
    const int nv0 = (nblk - 16) * 128;
#pragma unroll
    for (int mt = 0; mt < 8; ++mt)
#pragma unroll
      for (int nt = 0; nt < 2; ++nt) {
        const int col = wc * 32 + nt * 16 + L;
#pragma unroll
        for (int r = 0; r < 4; ++r) {
          int tok = wr * 128 + mt * 16 + Q4 * 4 + r;
          int pcm = (tok & ~31) | ((tok & 15) << 1) | ((tok >> 4) & 1);
          T[col * 264 + pcm] = f2bf(acc[mt][nt][r]);
        }
      }
    __syncthreads();
#pragma unroll
    for (int it2 = 0; it2 < 8; ++it2) {
      int slot = it2 * 512 + tid;
      int col = slot >> 5, ch = slot & 31;
      int nc = nv0 + col;
      *(short8*)(vtg +
                 (((size_t)((bb * 16 + (nc >> 6)) * 64 + (nc & 63))) << 11) +
                 ntok0 + ch * 8) = *(const short8*)&T[col * 264 + ch * 8];
    }
  }
}

// ---------------------------------------------------------------------------
// Output GEMM: grid 32x8 = 256 blocks (exactly 1 full round of 256 CUs).
// ---------------------------------------------------------------------------
__global__ __launch_bounds__(512, 2) void gemm_out_kernel(
    const unsigned short* __restrict__ A, const unsigned short* __restrict__ BT,
    const float* __restrict__ bias, float* __restrict__ C) {
  __shared__ __align__(16) unsigned char smem[147456];
  unsigned short* smemS = (unsigned short*)smem;

  const int tid = threadIdx.x;
  const int wave = tid >> 6, lane = tid & 63;
  const int Q4 = lane >> 4, L = lane & 15;
  const int wr = wave >> 2, wc = wave & 3;

  const int flat = blockIdx.y * 8 + blockIdx.x;
  const int swz = (flat & 7) * 32 + (flat >> 3);
  const int m0 = (swz >> 3) * 256, n0 = (swz & 7) * 128;

  floatx4 acc[8][2];
  core256x128(A, BT, smemS, m0, n0, acc);

#pragma unroll
  for (int mt = 0; mt < 8; ++mt) {
#pragma unroll
    for (int nt = 0; nt < 2; ++nt) {
      int nc = n0 + wc * 32 + nt * 16 + L;
      float bv = bias[nc];
#pragma unroll
      for (int r = 0; r < 4; ++r) {
        int m = m0 + wr * 128 + mt * 16 + Q4 * 4 + r;
        C[(size_t)m * DMODEL + nc] = acc[mt][nt][r] + bv;
      }
    }
  }
}

#undef STAGE_TILE
#undef RD_A
#undef RD_B
#undef CLUSTER
#undef G_BAR
#undef G_LGKM0

// ---------------------------------------------------------------------------
// Flash attention, SWAPPED-QK^T (T12) + 2-STAGE CROSS-kc2 PIPELINE (T15).
// R10: removing setprio fences + qs-interleave gave 80.2->77.8 us (MfmaUtil
// 43.4, VALUBusy 49.6, VGPR only 64 of 128 cap). The compiler minimized
// registers instead of keeping both kc2 sub-tiles live, so the per-kc2 chain
// {ds_read K -> QK -> exp -> PV} still serializes the two pipes. This round:
// hoist all 8 K-frag ds_reads (both kc2) + vf(kc2=0), then
// QK0 -> QK1 -> exp0 -> PV0 -> read vf1 -> exp1 -> PV1 with named registers
// (static indices, rule #20). Scheduler can now run exp0 under QK1 and exp1
// under PV0. Per-accumulator MFMA order and all float values unchanged ->
// bitwise-identical output. Expect VGPR ~100-128, no scratch.
// LDS 32KB, grid 512, 8 waves, 2 blocks/CU. [Best prior: 77.8us @ R10.]
// ---------------------------------------------------------------------------
__global__ __launch_bounds__(512, 4) void attn_kernel(
    const unsigned short* __restrict__ Qb, const unsigned short* __restrict__ Kb,
    const unsigned short* __restrict__ Vtg, unsigned short* __restrict__ Op) {
  __shared__ __align__(16) unsigned short Ks[2][64 * 64];
  __shared__ __align__(16) unsigned short Vs[2][64 * 64];
  const int tid = threadIdx.x;
  const int wave = tid >> 6, lane = tid & 63;   // wave 0..7
  const int quad = lane >> 4, l16 = lane & 15;
  const int bh = blockIdx.x & 63, qt = blockIdx.x >> 6;  // qt 0..7
  const size_t base = (size_t)bh * SEQ * DHEAD;
  const int lrow = lane >> 3, ls = lane & 7;
  const int dblk = ls ^ (lrow & 7);
  const int sw = l16 & 7;

  const unsigned short* kbase = Kb + base;
  const unsigned short* vbase = Vtg + base;
  const int rowS = wave * 8 + lrow;  // staging row (chunk = wave)

  short8 onesf;
#pragma unroll
  for (int i = 0; i < 8; ++i) onesf[i] = (short)0x3F80;  // bf16 1.0

  short8 qf[2][2];
#pragma unroll
  for (int qs = 0; qs < 2; ++qs) {
    int qrow = qt * 256 + wave * 32 + qs * 16 + l16;
    qf[qs][0] = *(const short8*)(Qb + base + (size_t)qrow * DHEAD + quad * 8);
    qf[qs][1] =
        *(const short8*)(Qb + base + (size_t)qrow * DHEAD + 32 + quad * 8);
  }

  floatx4 o[2][4], lacc[2];
#pragma unroll
  for (int qs = 0; qs < 2; ++qs) {
    lacc[qs] = (floatx4){0.f, 0.f, 0.f, 0.f};
#pragma unroll
    for (int dt = 0; dt < 4; ++dt) o[qs][dt] = (floatx4){0.f, 0.f, 0.f, 0.f};
  }

  const int cA = (quad ^ sw) * 8;        // k-chunk col offset, kc2=0
  const int cB = ((4 + quad) ^ sw) * 8;  // k-chunk col offset, kc2=1

#define STAGE(buf, kc)                                                         \
  do {                                                                         \
    async_ld16(kbase + (size_t)((kc)*64 + rowS) * DHEAD + dblk * 8,            \
               &Ks[buf][wave * 512]);                                          \
    async_ld16(vbase + (size_t)rowS * SEQ + (kc)*64 + dblk * 8,                \
               &Vs[buf][wave * 512]);                                          \
  } while (0)

#define COMPUTE(buf)                                                           \
  do {                                                                         \
    /* -- hoisted K fragments, BOTH kc2 sub-tiles (8 ds_read_b128) -- */       \
    short8 kf0[4], kf1[4];                                                     \
    kf0[0] = *(short8*)(&Ks[buf][0] + (l16) * 64 + cA);                        \
    kf0[1] = *(short8*)(&Ks[buf][0] + (l16) * 64 + cB);                        \
    kf0[2] = *(short8*)(&Ks[buf][0] + (16 + l16) * 64 + cA);                   \
    kf0[3] = *(short8*)(&Ks[buf][0] + (16 + l16) * 64 + cB);                   \
    kf1[0] = *(short8*)(&Ks[buf][0] + (32 + l16) * 64 + cA);                   \
    kf1[1] = *(short8*)(&Ks[buf][0] + (32 + l16) * 64 + cB);                   \
    kf1[2] = *(short8*)(&Ks[buf][0] + (48 + l16) * 64 + cA);                   \
    kf1[3] = *(short8*)(&Ks[buf][0] + (48 + l16) * 64 + cB);                   \
    short8 vf0[4];                                                             \
    _Pragma("unroll") for (int dt = 0; dt < 4; ++dt) vf0[dt] =                 \
        *(short8*)(&Vs[buf][0] + (dt * 16 + l16) * 64 + cA);                   \
    /* -- QK kc2=0 -- */                                                       \
    floatx4 sA0[2], sA1[2];                                                    \
    _Pragma("unroll") for (int qs = 0; qs < 2; ++qs) {                         \
      sA0[qs] = (floatx4){0.f, 0.f, 0.f, 0.f};                                 \
      sA1[qs] = (floatx4){0.f, 0.f, 0.f, 0.f};                                 \
      sA0[qs] = __builtin_amdgcn_mfma_f32_16x16x32_bf16(kf0[0], qf[qs][0],     \
                                                        sA0[qs], 0, 0, 0);     \
      sA0[qs] = __builtin_amdgcn_mfma_f32_16x16x32_bf16(kf0[1], qf[qs][1],     \
                                                        sA0[qs], 0, 0, 0);     \
      sA1[qs] = __builtin_amdgcn_mfma_f32_16x16x32_bf16(kf0[2], qf[qs][0],     \
                                                        sA1[qs], 0, 0, 0);     \
      sA1[qs] = __builtin_amdgcn_mfma_f32_16x16x32_bf16(kf0[3], qf[qs][1],     \
                                                        sA1[qs], 0, 0, 0);     \
    }                                                                          \
    /* -- QK kc2=1 (independent; overlaps exp0 below) -- */                    \
    floatx4 sB0[2], sB1[2];                                                    \
    _Pragma("unroll") for (int qs = 0; qs < 2; ++qs) {                         \
      sB0[qs] = (floatx4){0.f, 0.f, 0.f, 0.f};                                 \
      sB1[qs] = (floatx4){0.f, 0.f, 0.f, 0.f};                                 \
      sB0[qs] = __builtin_amdgcn_mfma_f32_16x16x32_bf16(kf1[0], qf[qs][0],     \
                                                        sB0[qs], 0, 0, 0);     \
      sB0[qs] = __builtin_amdgcn_mfma_f32_16x16x32_bf16(kf1[1], qf[qs][1],     \
                                                        sB0[qs], 0, 0, 0);     \
      sB1[qs] = __builtin_amdgcn_mfma_f32_16x16x32_bf16(kf1[2], qf[qs][0],     \
                                                        sB1[qs], 0, 0, 0);     \
      sB1[qs] = __builtin_amdgcn_mfma_f32_16x16x32_bf16(kf1[3], qf[qs][1],     \
                                                        sB1[qs], 0, 0, 0);     \
    }                                                                          \
    /* -- exp/pack kc2=0 -- */                                                 \
    short8 pf0[2];                                                             \
    _Pragma("unroll") for (int qs = 0; qs < 2; ++qs) {                         \
      union { short8 s8; u32 u[4]; } pu;                                       \
      _Pragma("unroll") for (int r = 0; r < 4; ++r)                            \
        pu.u[r] = pack_bf16(fast_exp2(sA0[qs][r]), fast_exp2(sA1[qs][r]));     \
      pf0[qs] = pu.s8;                                                         \
    }                                                                          \
    /* -- PV kc2=0 -- */                                                       \
    _Pragma("unroll") for (int qs = 0; qs < 2; ++qs) {                         \
      lacc[qs] = __builtin_amdgcn_mfma_f32_16x16x32_bf16(pf0[qs], onesf,       \
                                                         lacc[qs], 0, 0, 0);   \
      _Pragma("unroll") for (int dt = 0; dt < 4; ++dt) o[qs][dt] =             \
          __builtin_amdgcn_mfma_f32_16x16x32_bf16(pf0[qs], vf0[dt],            \
                                                  o[qs][dt], 0, 0, 0);         \
    }                                                                          \
    /* -- V fragments kc2=1; exp/pack kc2=1 (overlaps PV0) -- */               \
    short8 vf1[4];                                                             \
    _Pragma("unroll") for (int dt = 0; dt < 4; ++dt) vf1[dt] =                 \
        *(short8*)(&Vs[buf][0] + (dt * 16 + l16) * 64 + cB);                   \
    short8 pf1[2];                                                             \
    _Pragma("unroll") for (int qs = 0; qs < 2; ++qs) {                         \
      union { short8 s8; u32 u[4]; } pu;                                       \
      _Pragma("unroll") for (int r = 0; r < 4; ++r)                            \
        pu.u[r] = pack_bf16(fast_exp2(sB0[qs][r]), fast_exp2(sB1[qs][r]));     \
      pf1[qs] = pu.s8;                                                         \
    }                                                                          \
    /* -- PV kc2=1 -- */                                                       \
    _Pragma("unroll") for (int qs = 0; qs < 2; ++qs) {                         \
      lacc[qs] = __builtin_amdgcn_mfma_f32_16x16x32_bf16(pf1[qs], onesf,       \
                                                         lacc[qs], 0, 0, 0);   \
      _Pragma("unroll") for (int dt = 0; dt < 4; ++dt) o[qs][dt] =             \
          __builtin_amdgcn_mfma_f32_16x16x32_bf16(pf1[qs], vf1[dt],            \
                                                  o[qs][dt], 0, 0, 0);         \
    }                                                                          \
  } while (0)

  STAGE(0, 0);
  for (int kc = 0; kc < SEQ / 64; kc += 2) {
    __syncthreads();  // buf0 loads complete; all waves done reading buf1
    if (kc + 1 < SEQ / 64) STAGE(1, kc + 1);
    COMPUTE(0);
    __syncthreads();  // buf1 loads complete; all waves done reading buf0
    if (kc + 2 < SEQ / 64) STAGE(0, kc + 2);
    COMPUTE(1);
  }
#undef STAGE
#undef COMPUTE

  const int b = bh >> 4, h = bh & 15;
#pragma unroll
  for (int qs = 0; qs < 2; ++qs) {
#pragma unroll
    for (int r = 0; r < 4; ++r) {
      float inv = 1.f / lacc[qs][r];
      int n = qt * 256 + wave * 32 + qs * 16 + quad * 4 + r;
      size_t rowbase = ((size_t)(b * SEQ + n)) * DMODEL + h * DHEAD;
#pragma unroll
      for (int dt = 0; dt < 4; ++dt)
        Op[rowbase + dt * 16 + l16] = f2bf(o[qs][dt][r] * inv);
    }
  }
}

extern "C" void kernel_launch(void* const* d_in, const int* in_sizes, int n_in,
                              void* d_out, int out_size, void* d_ws,
                              size_t ws_size, hipStream_t stream) {
  const float* x = (const float*)d_in[0];
  const float* w_qkv = (const float*)d_in[1];
  const float* w_out = (const float*)d_in[2];
  const float* b_out = (const float*)d_in[3];
  float* out = (float*)d_out;

  unsigned short* ws = (unsigned short*)d_ws;
  unsigned short* xb = ws;                         // 8388608
  unsigned short* wqkvT = xb + 8388608;            // 3145728  [3072][1024]
  unsigned short* woutT = wqkvT + 3145728;         // 1048576  [1024][1024]
  unsigned short* qb = woutT + 1048576;            // [B,H,N,64] (pre-scaled)
  unsigned short* kb = qb + QKV_ELEMS;             // [B,H,N,64]
  unsigned short* vtg = kb + QKV_ELEMS;            // [B,H,64,N] permuted cols
  unsigned short* op = vtg + QKV_ELEMS;            // [B,N,1024]

  prep_kernel<<<dim3(12288), dim3(256), 0, stream>>>(x, w_qkv, w_out, xb,
                                                     wqkvT, woutT);
  gemm_qkv_kernel<<<dim3(24, 32), dim3(512), 0, stream>>>(xb, wqkvT, qb, vtg);
  attn_kernel<<<dim3(512), dim3(512), 0, stream>>>(qb, kb, vtg, op);
  gemm_out_kernel<<<dim3(8, 32), dim3(512), 0, stream>>>(op, woutT, b_out, out);
}

// Round 12
// 240.511 us; speedup vs baseline: 1.0656x; 1.0364x over previous
//
#include <hip/hip_runtime.h>
#include <math.h>

#define BATCH 4
#define SEQ   2048
#define DMODEL 1024
#define HEADS 16
#define DHEAD 64
#define SCALE 0.03125f                 // DIM^-0.5 = 1/32
#define KEXP  0.045084220027780106f    // SCALE * log2(e)
#define QKV_ELEMS (BATCH * HEADS * SEQ * DHEAD)  // 8388608 per tensor

typedef __attribute__((ext_vector_type(8))) short short8;
typedef __attribute__((ext_vector_type(4))) float floatx4;
typedef unsigned int u32;

__device__ __forceinline__ unsigned short f2bf(float f) {
  union { float f; unsigned u; } v;
  v.f = f;
  return (unsigned short)((v.u + 0x7FFFu + ((v.u >> 16) & 1u)) >> 16);
}

__device__ __forceinline__ float fast_exp2(float x) {
#if __has_builtin(__builtin_amdgcn_exp2f)
  return __builtin_amdgcn_exp2f(x);
#else
  return __expf(x * 0.6931471805599453f);
#endif
}

// pack two fp32 -> bf16x2 in one u32 (low = p0, high = p1)
__device__ __forceinline__ u32 pack_bf16(float p0, float p1) {
#if __has_builtin(__builtin_amdgcn_cvt_pk_bf16_f32)
  typedef __bf16 bf16x2 __attribute__((ext_vector_type(2)));
  bf16x2 t = __builtin_amdgcn_cvt_pk_bf16_f32(p0, p1);
  u32 r;
  __builtin_memcpy(&r, &t, 4);
  return r;
#else
  u32 a0 = __float_as_uint(p0) + 0x8000u;
  u32 a1 = __float_as_uint(p1) + 0x8000u;
  return __builtin_amdgcn_perm(a1, a0, 0x07060302);
#endif
}

// async global->LDS, 16B per lane; lds dest is wave-uniform base + lane*16.
__device__ __forceinline__ void async_ld16(const void* g, void* l) {
  __builtin_amdgcn_global_load_lds(
      (const __attribute__((address_space(1))) u32*)g,
      (__attribute__((address_space(3))) u32*)l, 16, 0, 0);
}

// ---------------------------------------------------------------------------
// Merged prep: x->bf16 (blocks 0..8191), wqkv transpose (8192..11263),
// wout transpose (11264..12287).
// ---------------------------------------------------------------------------
__device__ __forceinline__ void trans_tile(const float* __restrict__ W,
                                           unsigned short* __restrict__ WT,
                                           int K, int N, int n0, int k0,
                                           float (*tile)[33]) {
  const int tx = threadIdx.x & 31, ty = threadIdx.x >> 5;  // ty 0..7
#pragma unroll
  for (int i = 0; i < 4; ++i)
    tile[ty + i * 8][tx] = W[(size_t)(k0 + ty + i * 8) * N + n0 + tx];
  __syncthreads();
#pragma unroll
  for (int i = 0; i < 4; ++i)
    WT[(size_t)(n0 + ty + i * 8) * K + k0 + tx] = f2bf(tile[tx][ty + i * 8]);
}

__global__ __launch_bounds__(256) void prep_kernel(
    const float* __restrict__ x, const float* __restrict__ wqkv,
    const float* __restrict__ wout, unsigned short* __restrict__ xb,
    unsigned short* __restrict__ wqkvT, unsigned short* __restrict__ woutT) {
  __shared__ float tile[32][33];
  const int bx = blockIdx.x;
  if (bx < 8192) {
    size_t i = ((size_t)bx * 256 + threadIdx.x) * 4;
    float4 v = *(const float4*)(x + i);
    ushort4 o;
    o.x = f2bf(v.x); o.y = f2bf(v.y); o.z = f2bf(v.z); o.w = f2bf(v.w);
    *(ushort4*)(xb + i) = o;
  } else if (bx < 11264) {
    int t = bx - 8192;
    trans_tile(wqkv, wqkvT, 1024, 3072, (t % 96) * 32, (t / 96) * 32, tile);
  } else {
    int t = bx - 11264;
    trans_tile(wout, woutT, 1024, 1024, (t % 32) * 32, (t / 32) * 32, tile);
  }
}

// ---------------------------------------------------------------------------
// Shared GEMM core: 256x128 tile, BK=64, 512 threads (8 waves, 2M x 4N),
// TRIPLE-buffered LDS (3 x 48KB = 144KB), 2 phases per K-tile, counted
// vmcnt(6) (stage tile u+2 at Ph1 of iter u; oldest 6 loads = tile u+1
// guaranteed at Ph2-end vmcnt), setprio around 16-MFMA clusters, XOR k-chunk
// swizzle on staging source + fragment reads.
// ---------------------------------------------------------------------------
#define G_BAR() __builtin_amdgcn_s_barrier()
#define G_LGKM0() asm volatile("s_waitcnt lgkmcnt(0)" ::: "memory")

#define STAGE_TILE(t)                                                          \
  do {                                                                         \
    const unsigned short* Ab =                                                 \
        A + (size_t)(m0 + srow) * 1024 + (t) * 64 + schunk * 8;                \
    const unsigned short* Bb =                                                 \
        BT + (size_t)(n0 + srow) * 1024 + (t) * 64 + schunk * 8;               \
    unsigned short* sa = smemS + ((t) % 3) * 24576;                            \
    unsigned short* sb = sa + 16384;                                           \
    async_ld16(Ab, sa + tid * 8);                                              \
    async_ld16(Ab + 64 * 1024, sa + 4096 + tid * 8);                           \
    async_ld16(Ab + 128 * 1024, sa + 8192 + tid * 8);                          \
    async_ld16(Ab + 192 * 1024, sa + 12288 + tid * 8);                         \
    async_ld16(Bb, sb + tid * 8);                                              \
    async_ld16(Bb + 64 * 1024, sb + 4096 + tid * 8);                           \
  } while (0)

#define RD_A(SAp, mh)                                                          \
  do {                                                                         \
    _Pragma("unroll") for (int mi = 0; mi < 4; ++mi) {                         \
      a[mi][0] = *(const short8*)((SAp) + rowA + (mh)*4096 + mi * 1024 + cof0);\
      a[mi][1] = *(const short8*)((SAp) + rowA + (mh)*4096 + mi * 1024 + cof1);\
    }                                                                          \
  } while (0)

#define RD_B(SBp)                                                              \
  do {                                                                         \
    _Pragma("unroll") for (int ni = 0; ni < 2; ++ni) {                         \
      b[ni][0] = *(const short8*)((SBp) + rowB + ni * 1024 + cof0);            \
      b[ni][1] = *(const short8*)((SBp) + rowB + ni * 1024 + cof1);            \
    }                                                                          \
  } while (0)

#define CLUSTER(mh)                                                            \
  do {                                                                         \
    __builtin_amdgcn_s_setprio(1);                                             \
    _Pragma("unroll") for (int mi = 0; mi < 4; ++mi) {                         \
      _Pragma("unroll") for (int ni = 0; ni < 2; ++ni) {                       \
        acc[(mh)*4 + mi][ni] = __builtin_amdgcn_mfma_f32_16x16x32_bf16(        \
            a[mi][0], b[ni][0], acc[(mh)*4 + mi][ni], 0, 0, 0);                \
        acc[(mh)*4 + mi][ni] = __builtin_amdgcn_mfma_f32_16x16x32_bf16(        \
            a[mi][1], b[ni][1], acc[(mh)*4 + mi][ni], 0, 0, 0);                \
      }                                                                        \
    }                                                                          \
    __builtin_amdgcn_s_setprio(0);                                             \
  } while (0)

__device__ __forceinline__ void core256x128(
    const unsigned short* __restrict__ A, const unsigned short* __restrict__ BT,
    unsigned short* smemS, int m0, int n0, floatx4 (&acc)[8][2]) {
  const int tid = threadIdx.x;            // 0..511
  const int wave = tid >> 6, lane = tid & 63;
  const int Q4 = lane >> 4, L = lane & 15;
  const int wr = wave >> 2, wc = wave & 3;
  const int srow = tid >> 3;                   // 0..63
  const int schunk = (tid & 7) ^ (srow & 7);   // swizzled k-chunk
  const int xorL = L & 7;
  const int cof0 = (Q4 ^ xorL) * 8;
  const int cof1 = ((4 + Q4) ^ xorL) * 8;
  const int rowA = wr * 8192 + L * 64;         // wave M-half base (rows*64)
  const int rowB = wc * 2048 + L * 64;         // wave N-slab base

  short8 a[4][2], b[2][2];
#pragma unroll
  for (int mt = 0; mt < 8; ++mt)
#pragma unroll
    for (int nt = 0; nt < 2; ++nt) acc[mt][nt] = (floatx4){0.f, 0.f, 0.f, 0.f};

  STAGE_TILE(0);
  STAGE_TILE(1);
  asm volatile("s_waitcnt vmcnt(6)" ::: "memory");
  G_BAR();

#pragma unroll
  for (int u = 0; u < 16; ++u) {
    unsigned short* SA = smemS + (u % 3) * 24576;
    unsigned short* SB = SA + 16384;
    // ---- Ph1: read A(mh0)+B of tile u; stage tile u+2
    RD_A(SA, 0);
    RD_B(SB);
    if (u + 2 < 16) STAGE_TILE(u + 2);
    G_BAR(); G_LGKM0();
    CLUSTER(0);
    G_BAR();
    // ---- Ph2: read A(mh1); counted vmcnt before closing barrier
    RD_A(SA, 1);
    G_BAR(); G_LGKM0();
    CLUSTER(1);
    if (u + 2 < 16) asm volatile("s_waitcnt vmcnt(6)" ::: "memory");
    else            asm volatile("s_waitcnt vmcnt(0)" ::: "memory");
    G_BAR();
  }
}

// ---------------------------------------------------------------------------
// QKV GEMM: grid 32x24 = 768 blocks (exactly 3 full rounds of 256 CUs).
// nblk 0..7 -> Q (scaled by KEXP), 8..15 -> K (repacked to [B,H,N,64] rows),
// 16..23 -> V transposed into vtg [B,H,64,N] (pc-permuted tokens).
// ---------------------------------------------------------------------------
__global__ __launch_bounds__(512, 2) void gemm_qkv_kernel(
    const unsigned short* __restrict__ A, const unsigned short* __restrict__ BT,
    unsigned short* __restrict__ qk, unsigned short* __restrict__ vtg) {
  __shared__ __align__(16) unsigned char smem[147456];  // 3 x 48KB
  unsigned short* smemS = (unsigned short*)smem;

  const int tid = threadIdx.x;
  const int wave = tid >> 6, lane = tid & 63;
  const int Q4 = lane >> 4, L = lane & 15;
  const int wr = wave >> 2, wc = wave & 3;

  // bijective XCD swizzle over 768 blocks (768 % 8 == 0)
  const int flat = blockIdx.y * 24 + blockIdx.x;
  const int swz = (flat & 7) * 96 + (flat >> 3);
  const int mblk = swz / 24, nblk = swz % 24;
  const int m0 = mblk * 256, n0 = nblk * 128;

  floatx4 acc[8][2];
  core256x128(A, BT, smemS, m0, n0, acc);

  // ------------------------------- epilogue -------------------------------
  const int bb = m0 >> 11;
  const int ntok0 = m0 & 2047;
  unsigned short* T = smemS;

  if (nblk < 16) {
    // Q/K: repack to [B,H,N,64] rows via T[256][136] (single pass)
    const float qsc = (nblk < 8) ? KEXP : 1.0f;
    unsigned short* dst = qk + (size_t)(nblk >> 3) * QKV_ELEMS;
    const int h0 = (nblk & 7) * 2;
#pragma unroll
    for (int mt = 0; mt < 8; ++mt)
#pragma unroll
      for (int nt = 0; nt < 2; ++nt) {
        const int col = wc * 32 + nt * 16 + L;
        const int tokl = wr * 128 + mt * 16 + Q4 * 4;
#pragma unroll
        for (int r = 0; r < 4; ++r)
          T[(tokl + r) * 136 + col] = f2bf(acc[mt][nt][r] * qsc);
      }
    __syncthreads();
#pragma unroll
    for (int it2 = 0; it2 < 8; ++it2) {
      int slot = it2 * 512 + tid;
      int tok = slot >> 4, ch = slot & 15;
      int hh = ch >> 3, inner = ch & 7;
      *(short8*)(dst +
                 (((size_t)((bb * 16 + h0 + hh) * 2048 + ntok0 + tok)) << 6) +
                 inner * 8) = *(const short8*)&T[tok * 136 + hh * 64 + inner * 8];
    }
  } else {
    // V: transpose to vtg [B,H,64,N] with pc-permuted tokens via T[128][264]
    const int nv0 = (nblk - 16) * 128;
#pragma unroll
    for (int mt = 0; mt < 8; ++mt)
#pragma unroll
      for (int nt = 0; nt < 2; ++nt) {
        const int col = wc * 32 + nt * 16 + L;
#pragma unroll
        for (int r = 0; r < 4; ++r) {
          int tok = wr * 128 + mt * 16 + Q4 * 4 + r;
          int pcm = (tok & ~31) | ((tok & 15) << 1) | ((tok >> 4) & 1);
          T[col * 264 + pcm] = f2bf(acc[mt][nt][r]);
        }
      }
    __syncthreads();
#pragma unroll
    for (int it2 = 0; it2 < 8; ++it2) {
      int slot = it2 * 512 + tid;
      int col = slot >> 5, ch = slot & 31;
      int nc = nv0 + col;
      *(short8*)(vtg +
                 (((size_t)((bb * 16 + (nc >> 6)) * 64 + (nc & 63))) << 11) +
                 ntok0 + ch * 8) = *(const short8*)&T[col * 264 + ch * 8];
    }
  }
}

// ---------------------------------------------------------------------------
// Output GEMM: grid 32x8 = 256 blocks (exactly 1 full round of 256 CUs).
// ---------------------------------------------------------------------------
__global__ __launch_bounds__(512, 2) void gemm_out_kernel(
    const unsigned short* __restrict__ A, const unsigned short* __restrict__ BT,
    const float* __restrict__ bias, float* __restrict__ C) {
  __shared__ __align__(16) unsigned char smem[147456];
  unsigned short* smemS = (unsigned short*)smem;

  const int tid = threadIdx.x;
  const int wave = tid >> 6, lane = tid & 63;
  const int Q4 = lane >> 4, L = lane & 15;
  const int wr = wave >> 2, wc = wave & 3;

  const int flat = blockIdx.y * 8 + blockIdx.x;
  const int swz = (flat & 7) * 32 + (flat >> 3);
  const int m0 = (swz >> 3) * 256, n0 = (swz & 7) * 128;

  floatx4 acc[8][2];
  core256x128(A, BT, smemS, m0, n0, acc);

#pragma unroll
  for (int mt = 0; mt < 8; ++mt) {
#pragma unroll
    for (int nt = 0; nt < 2; ++nt) {
      int nc = n0 + wc * 32 + nt * 16 + L;
      float bv = bias[nc];
#pragma unroll
      for (int r = 0; r < 4; ++r) {
        int m = m0 + wr * 128 + mt * 16 + Q4 * 4 + r;
        C[(size_t)m * DMODEL + nc] = acc[mt][nt][r] + bv;
      }
    }
  }
}

#undef STAGE_TILE
#undef RD_A
#undef RD_B
#undef CLUSTER
#undef G_BAR
#undef G_LGKM0

// ---------------------------------------------------------------------------
// Flash attention, SWAPPED-QK^T (T12) + ILP-INTERLEAVED COMPUTE.
// [REVERT of R11: the cross-kc2 hoist kept VGPR at 64 and SPILLED the
// hoisted state to scratch (FETCH 25->34 GB, WRITE 16->31 MB, 77.8->91.3us).
// This R10 form is the best measured: attn 77.8us, MfmaUtil 43.4, VALUBusy
// 49.6, 0 bank conflicts, FETCH 25 GB. Per-qs interleave with no setprio
// fences lets the scheduler hoist exp(qs0) under QK(qs1) and PV(qs0) under
// exp(qs1) WITHOUT widening live ranges past the allocator's comfort.]
// LDS 32KB, grid 512, 8 waves, 2 blocks/CU.
// ---------------------------------------------------------------------------
__global__ __launch_bounds__(512, 4) void attn_kernel(
    const unsigned short* __restrict__ Qb, const unsigned short* __restrict__ Kb,
    const unsigned short* __restrict__ Vtg, unsigned short* __restrict__ Op) {
  __shared__ __align__(16) unsigned short Ks[2][64 * 64];
  __shared__ __align__(16) unsigned short Vs[2][64 * 64];
  const int tid = threadIdx.x;
  const int wave = tid >> 6, lane = tid & 63;   // wave 0..7
  const int quad = lane >> 4, l16 = lane & 15;
  const int bh = blockIdx.x & 63, qt = blockIdx.x >> 6;  // qt 0..7
  const size_t base = (size_t)bh * SEQ * DHEAD;
  const int lrow = lane >> 3, ls = lane & 7;
  const int dblk = ls ^ (lrow & 7);
  const int sw = l16 & 7;

  const unsigned short* kbase = Kb + base;
  const unsigned short* vbase = Vtg + base;
  const int rowS = wave * 8 + lrow;  // staging row (chunk = wave)

  short8 onesf;
#pragma unroll
  for (int i = 0; i < 8; ++i) onesf[i] = (short)0x3F80;  // bf16 1.0

  short8 qf[2][2];
#pragma unroll
  for (int qs = 0; qs < 2; ++qs) {
    int qrow = qt * 256 + wave * 32 + qs * 16 + l16;
    qf[qs][0] = *(const short8*)(Qb + base + (size_t)qrow * DHEAD + quad * 8);
    qf[qs][1] =
        *(const short8*)(Qb + base + (size_t)qrow * DHEAD + 32 + quad * 8);
  }

  floatx4 o[2][4], lacc[2];
#pragma unroll
  for (int qs = 0; qs < 2; ++qs) {
    lacc[qs] = (floatx4){0.f, 0.f, 0.f, 0.f};
#pragma unroll
    for (int dt = 0; dt < 4; ++dt) o[qs][dt] = (floatx4){0.f, 0.f, 0.f, 0.f};
  }

#define STAGE(buf, kc)                                                         \
  do {                                                                         \
    async_ld16(kbase + (size_t)((kc)*64 + rowS) * DHEAD + dblk * 8,            \
               &Ks[buf][wave * 512]);                                          \
    async_ld16(vbase + (size_t)rowS * SEQ + (kc)*64 + dblk * 8,                \
               &Vs[buf][wave * 512]);                                          \
  } while (0)

#define COMPUTE(buf)                                                           \
  do {                                                                         \
    _Pragma("unroll") for (int kc2 = 0; kc2 < 2; ++kc2) {                      \
      const int krow = kc2 * 32;                                               \
      short8 kf00 =                                                            \
          *(short8*)(&Ks[buf][0] + (krow + l16) * 64 + ((quad ^ sw) * 8));     \
      short8 kf01 = *(short8*)(&Ks[buf][0] + (krow + l16) * 64 +               \
                               (((4 + quad) ^ sw) * 8));                       \
      short8 kf10 = *(short8*)(&Ks[buf][0] + (krow + 16 + l16) * 64 +          \
                               ((quad ^ sw) * 8));                             \
      short8 kf11 = *(short8*)(&Ks[buf][0] + (krow + 16 + l16) * 64 +          \
                               (((4 + quad) ^ sw) * 8));                       \
      short8 vf[4];                                                            \
      _Pragma("unroll") for (int dt = 0; dt < 4; ++dt) vf[dt] =                \
          *(short8*)(&Vs[buf][0] + (dt * 16 + l16) * 64 +                      \
                     (((kc2 * 4 + quad) ^ sw) * 8));                           \
      floatx4 s0[2], s1[2];                                                    \
      _Pragma("unroll") for (int qs = 0; qs < 2; ++qs) {                       \
        s0[qs] = (floatx4){0.f, 0.f, 0.f, 0.f};                                \
        s1[qs] = (floatx4){0.f, 0.f, 0.f, 0.f};                                \
        s0[qs] = __builtin_amdgcn_mfma_f32_16x16x32_bf16(kf00, qf[qs][0],      \
                                                         s0[qs], 0, 0, 0);     \
        s0[qs] = __builtin_amdgcn_mfma_f32_16x16x32_bf16(kf01, qf[qs][1],      \
                                                         s0[qs], 0, 0, 0);     \
        s1[qs] = __builtin_amdgcn_mfma_f32_16x16x32_bf16(kf10, qf[qs][0],      \
                                                         s1[qs], 0, 0, 0);     \
        s1[qs] = __builtin_amdgcn_mfma_f32_16x16x32_bf16(kf11, qf[qs][1],      \
                                                         s1[qs], 0, 0, 0);     \
      }                                                                        \
      short8 pf[2];                                                            \
      _Pragma("unroll") for (int qs = 0; qs < 2; ++qs) {                       \
        union { short8 s8; u32 u[4]; } pu;                                     \
        _Pragma("unroll") for (int r = 0; r < 4; ++r) {                        \
          pu.u[r] = pack_bf16(fast_exp2(s0[qs][r]), fast_exp2(s1[qs][r]));     \
        }                                                                      \
        pf[qs] = pu.s8;                                                        \
      }                                                                        \
      _Pragma("unroll") for (int qs = 0; qs < 2; ++qs) {                       \
        lacc[qs] = __builtin_amdgcn_mfma_f32_16x16x32_bf16(pf[qs], onesf,      \
                                                           lacc[qs], 0, 0, 0); \
        _Pragma("unroll") for (int dt = 0; dt < 4; ++dt) o[qs][dt] =           \
            __builtin_amdgcn_mfma_f32_16x16x32_bf16(pf[qs], vf[dt],            \
                                                    o[qs][dt], 0, 0, 0);       \
      }                                                                        \
    }                                                                          \
  } while (0)

  STAGE(0, 0);
  for (int kc = 0; kc < SEQ / 64; kc += 2) {
    __syncthreads();  // buf0 loads complete; all waves done reading buf1
    if (kc + 1 < SEQ / 64) STAGE(1, kc + 1);
    COMPUTE(0);
    __syncthreads();  // buf1 loads complete; all waves done reading buf0
    if (kc + 2 < SEQ / 64) STAGE(0, kc + 2);
    COMPUTE(1);
  }
#undef STAGE
#undef COMPUTE

  const int b = bh >> 4, h = bh & 15;
#pragma unroll
  for (int qs = 0; qs < 2; ++qs) {
#pragma unroll
    for (int r = 0; r < 4; ++r) {
      float inv = 1.f / lacc[qs][r];
      int n = qt * 256 + wave * 32 + qs * 16 + quad * 4 + r;
      size_t rowbase = ((size_t)(b * SEQ + n)) * DMODEL + h * DHEAD;
#pragma unroll
      for (int dt = 0; dt < 4; ++dt)
        Op[rowbase + dt * 16 + l16] = f2bf(o[qs][dt][r] * inv);
    }
  }
}

extern "C" void kernel_launch(void* const* d_in, const int* in_sizes, int n_in,
                              void* d_out, int out_size, void* d_ws,
                              size_t ws_size, hipStream_t stream) {
  const float* x = (const float*)d_in[0];
  const float* w_qkv = (const float*)d_in[1];
  const float* w_out = (const float*)d_in[2];
  const float* b_out = (const float*)d_in[3];
  float* out = (float*)d_out;

  unsigned short* ws = (unsigned short*)d_ws;
  unsigned short* xb = ws;                         // 8388608
  unsigned short* wqkvT = xb + 8388608;            // 3145728  [3072][1024]
  unsigned short* woutT = wqkvT + 3145728;         // 1048576  [1024][1024]
  unsigned short* qb = woutT + 1048576;            // [B,H,N,64] (pre-scaled)
  unsigned short* kb = qb + QKV_ELEMS;             // [B,H,N,64]
  unsigned short* vtg = kb + QKV_ELEMS;            // [B,H,64,N] permuted cols
  unsigned short* op = vtg + QKV_ELEMS;            // [B,N,1024]

  prep_kernel<<<dim3(12288), dim3(256), 0, stream>>>(x, w_qkv, w_out, xb,
                                                     wqkvT, woutT);
  gemm_qkv_kernel<<<dim3(24, 32), dim3(512), 0, stream>>>(xb, wqkvT, qb, vtg);
  attn_kernel<<<dim3(512), dim3(512), 0, stream>>>(qb, kb, vtg, op);
  gemm_out_kernel<<<dim3(8, 32), dim3(512), 0, stream>>>(op, woutT, b_out, out);
}